// Round 15
// baseline (221.766 us; speedup 1.0000x reference)
//
#include <hip/hip_runtime.h>
#include <hip/hip_bf16.h>

// SCNN round 15:
//  - k_gemm: wave tile 64x128 -> 16 MFMA : 8 ds_read_b128 per K16 phase
//    (2x r14's MFMA-per-barrier density, matching the m201 template's).
//    BM=128 BN=512 BK=32, 512 thr / 8 waves (2Mx4N), ring-3 x 48KB = 144KB
//    LDS, stage split across the 2 phases, vmcnt(6) at iter end.
//    192 uniform 16-iter blocks (chunk 512: sk {4,8,4}) - same K-decomposition
//    as r13 -> bit-identical output.
//  - pf packed {4,8,4} (48MB) + r13 epilogues; k_pre / MLP unchanged.

#define B_    32
#define S_    8
#define BS_   256
#define F_    4
#define IN_   8192
#define H_    1024
#define OUT_  256

#define L_TOT  25165824LL
#define LOFF1  4194304LL
#define LOFF2  20971520LL

// packed pf float offsets
#define PF_B1  2097152LL      // 4*256*2048
#define PF_B2  10485760LL     // PF_B1 + 8*256*4096
#define PF_TOT 12582912LL     // 48MB

typedef __attribute__((ext_vector_type(8)))  short bf16x8;
typedef __attribute__((ext_vector_type(4)))  short short4v;
typedef __attribute__((ext_vector_type(8)))  short short8v;
typedef __attribute__((ext_vector_type(16))) float f32x16;
typedef __attribute__((ext_vector_type(4)))  float f32x4;

typedef const __attribute__((address_space(1))) void* gas_ptr;
typedef __attribute__((address_space(3))) void* las_ptr;

__device__ __forceinline__ void gload16(const void* g, void* s) {
    __builtin_amdgcn_global_load_lds((gas_ptr)g, (las_ptr)s, 16, 0, 0);
}

__device__ __forceinline__ unsigned short rne_bf16(float f) {
    unsigned int u = __builtin_bit_cast(unsigned int, f);
    u += 0x7FFFu + ((u >> 16) & 1u);
    return (unsigned short)(u >> 16);
}

// ---------------- fused prep: L->bf16, x->hi/lo, P/M ----------------
__global__ void k_pre(const float* __restrict__ L0, const float* __restrict__ L1,
                      const float* __restrict__ L2, unsigned short* __restrict__ Lb,
                      const float* __restrict__ x0, const float* __restrict__ x1,
                      const float* __restrict__ x2,
                      unsigned short* __restrict__ Xhi, unsigned short* __restrict__ Xlo,
                      const float* __restrict__ Wc0, const float* __restrict__ Wc1,
                      const float* __restrict__ Wc2, float* __restrict__ PM)
{
    const int bx = blockIdx.x, tid = threadIdx.x;
    if (bx < 3072) {
        const long long b0 = (long long)bx * 8192;
        const float* src; long long off;
        if (b0 < LOFF1)      { src = L0; off = 0; }
        else if (b0 < LOFF2) { src = L1; off = LOFF1; }
        else                 { src = L2; off = LOFF2; }
        const float* pb = src + (b0 - off) + tid * 8;
        #pragma unroll
        for (int u = 0; u < 4; ++u) {
            const float* p = pb + u * 2048;
            f32x4 a = __builtin_nontemporal_load((const f32x4*)p);
            f32x4 b = __builtin_nontemporal_load((const f32x4*)p + 1);
            short8v o;
            o[0] = (short)rne_bf16(a.x); o[1] = (short)rne_bf16(a.y);
            o[2] = (short)rne_bf16(a.z); o[3] = (short)rne_bf16(a.w);
            o[4] = (short)rne_bf16(b.x); o[5] = (short)rne_bf16(b.y);
            o[6] = (short)rne_bf16(b.z); o[7] = (short)rne_bf16(b.w);
            *(short8v*)(Lb + b0 + u * 2048 + tid * 8) = o;
        }
    } else if (bx < 3584) {
        const int base = (bx - 3072) * 4096 + tid * 8;
        #pragma unroll
        for (int u = 0; u < 2; ++u) {
            int e = base + u * 2048;
            int m = e >> 13, c = e & 8191;
            const float* src; int n, c0;
            if (c < 2048)      { src = x0; n = 2048; c0 = c; }
            else if (c < 6144) { src = x1; n = 4096; c0 = c - 2048; }
            else               { src = x2; n = 2048; c0 = c - 6144; }
            const float* p = src + (size_t)m * n + c0;
            f32x4 a = __builtin_nontemporal_load((const f32x4*)p);
            f32x4 b = __builtin_nontemporal_load((const f32x4*)p + 1);
            float v[8] = {a.x, a.y, a.z, a.w, b.x, b.y, b.z, b.w};
            short8v h, l;
            #pragma unroll
            for (int i = 0; i < 8; ++i) {
                unsigned short hb = rne_bf16(v[i]);
                float hf = __builtin_bit_cast(float, (unsigned int)hb << 16);
                h[i] = (short)hb;
                l[i] = (short)rne_bf16(v[i] - hf);
            }
            *(short8v*)(Xhi + (size_t)m * IN_ + c) = h;
            *(short8v*)(Xlo + (size_t)m * IN_ + c) = l;
        }
    } else {
        const int base = (bx - 3584) * 2048 + tid * 8;
        #pragma unroll
        for (int i = 0; i < 8; ++i) {
            int idx = base + i;
            int l = idx / IN_, n = idx % IN_;
            const float* Wc; int nb, j;
            if (n < 2048)      { Wc = Wc0; nb = 2048; j = n;        }
            else if (n < 6144) { Wc = Wc1; nb = 4096; j = n - 2048; }
            else               { Wc = Wc2; nb = 2048; j = n - 6144; }
            float p = 0.f, m = 0.f;
            #pragma unroll
            for (int f = 0; f < F_; ++f) {
                float w = Wc[(l * F_ + f) * nb + j];
                p += fmaxf(w, 0.f);
                m += fmaxf(-w, 0.f);
            }
            PM[(l * 2 + 0) * IN_ + n] = p;
            PM[(l * 2 + 1) * IN_ + n] = m;
        }
    }
}

// ---------------- MFMA GEMM: BM=128 BN=512 BK=32, wave 64x128, ring-3 ----------------
// 192 blocks, uniform 16 iters (chunk 512):
// bx<128: b1 (sk8 x 2mt x 8nt); 128-159: b0 (sk4 x 2mt x 4nt); 160-191: b2.
__global__ __launch_bounds__(512, 1) void k_gemm(
    const unsigned short* __restrict__ Xhi, const unsigned short* __restrict__ Xlo,
    const unsigned short* __restrict__ Lb,
    float* __restrict__ pf)
{
    __shared__ __attribute__((aligned(16))) char lds[3 * 49152];   // 144KB ring-3

    const int bx = blockIdx.x;
    int n_, noff, mt, nt, sk, ld; long long loff; size_t pbase;
    if (bx < 128) {                       // branch 1
        sk = bx & 7; int v = bx >> 3; mt = v & 1; nt = v >> 1;
        n_ = 4096; noff = 2048; loff = LOFF1; pbase = PF_B1; ld = 4096;
    } else if (bx < 160) {                // branch 0
        int u = bx - 128; sk = u & 3; mt = (u >> 2) & 1; nt = u >> 3;
        n_ = 2048; noff = 0; loff = 0; pbase = 0; ld = 2048;
    } else {                              // branch 2
        int u = bx - 160; sk = u & 3; mt = (u >> 2) & 1; nt = u >> 3;
        n_ = 2048; noff = 6144; loff = LOFF2; pbase = PF_B2; ld = 2048;
    }
    const int k0 = sk * 512;              // 16 iters of BK=32

    const int tid = threadIdx.x;

    // ----- staging (6 gload16/thread/iter), pre-swizzled source cols -----
    const int sg = ((tid & 3) ^ ((tid >> 3) & 3)) << 3;   // ushort offset
    const unsigned short* gAh = Xhi + (size_t)(mt * 128 + (tid >> 2)) * IN_ + noff + k0 + sg;
    const unsigned short* gAl = Xlo + (size_t)(mt * 128 + (tid >> 2)) * IN_ + noff + k0 + sg;
    const unsigned short* gB  = Lb + loff + (size_t)(nt * 512 + (tid >> 2)) * n_ + k0 + sg;
    const size_t b128r = (size_t)128 * n_;
    const int tb = tid * 16;

    // per-buffer layout: Ah [128][32] @0 (8K) | Al @8192 | B [512][32] @16384 (32K)
    #define ISS_H1(s, ko) do { char* _b = lds + (s) * 49152;                     \
        gload16(gAh + (ko), _b + tb);                                            \
        gload16(gAl + (ko), _b + 8192 + tb);                                     \
        gload16(gB + (ko),  _b + 16384 + tb); } while (0)
    #define ISS_H2(s, ko) do { char* _b = lds + (s) * 49152;                     \
        gload16(gB + (ko) + b128r,     _b + 16384 + 8192 + tb);                  \
        gload16(gB + (ko) + 2 * b128r, _b + 16384 + 16384 + tb);                 \
        gload16(gB + (ko) + 3 * b128r, _b + 16384 + 24576 + tb); } while (0)

    // ----- compute-side addressing: 8 waves 2Mx4N, wave tile 64x128 -----
    const int l = tid & 63, w = tid >> 6;
    const int l31 = l & 31, lh = l >> 5;
    const int wm = w >> 2, wn = w & 3;
    const int swz = (l31 >> 1) & 3;
    int aoff[2], boff[4];
    #pragma unroll
    for (int rb = 0; rb < 2; ++rb) aoff[rb] = (wm * 64 + rb * 32 + l31) * 64;
    #pragma unroll
    for (int cb = 0; cb < 4; ++cb) boff[cb] = 16384 + (wn * 128 + cb * 32 + l31) * 64;

    f32x16 acc[2][4];
    #pragma unroll
    for (int rb = 0; rb < 2; ++rb)
        #pragma unroll
        for (int cb = 0; cb < 4; ++cb)
            #pragma unroll
            for (int e = 0; e < 16; ++e) acc[rb][cb][e] = 0.f;

    #define PHASE(s, j) do {                                                     \
        const char* _b = lds + (s) * 49152;                                      \
        const int _sl = ((((j) * 2 + lh) ^ swz) << 4);                           \
        bf16x8 fah[2], fal[2], fb[4];                                            \
        _Pragma("unroll")                                                        \
        for (int rb = 0; rb < 2; ++rb) {                                         \
            fah[rb] = *(const bf16x8*)(_b + aoff[rb] + _sl);                     \
            fal[rb] = *(const bf16x8*)(_b + 8192 + aoff[rb] + _sl);              \
        }                                                                        \
        _Pragma("unroll")                                                        \
        for (int cb = 0; cb < 4; ++cb)                                           \
            fb[cb] = *(const bf16x8*)(_b + boff[cb] + _sl);                      \
        __builtin_amdgcn_s_setprio(1);                                           \
        _Pragma("unroll")                                                        \
        for (int rb = 0; rb < 2; ++rb)                                           \
            _Pragma("unroll")                                                    \
            for (int cb = 0; cb < 4; ++cb) {                                     \
                acc[rb][cb] = __builtin_amdgcn_mfma_f32_32x32x16_bf16(fal[rb], fb[cb], acc[rb][cb], 0, 0, 0); \
                acc[rb][cb] = __builtin_amdgcn_mfma_f32_32x32x16_bf16(fah[rb], fb[cb], acc[rb][cb], 0, 0, 0); \
            }                                                                    \
        __builtin_amdgcn_s_setprio(0); } while (0)

    // prologue: stage iters 0 and 1 (12 loads), sync iter 0
    ISS_H1(0, 0); ISS_H2(0, 0);
    ISS_H1(1, 32); ISS_H2(1, 32);
    asm volatile("s_waitcnt vmcnt(6)" ::: "memory");
    __builtin_amdgcn_s_barrier();
    asm volatile("" ::: "memory");

    for (int it = 0; it < 16; ++it) {
        const int cur = it % 3;
        const int nxt = (it + 2) % 3;
        const int ko = (it + 2) * 32;

        // phase 0: stage half of iter+2, compute j=0
        if (it + 2 < 16) ISS_H1(nxt, ko);
        __builtin_amdgcn_sched_barrier(0);
        PHASE(cur, 0);
        __builtin_amdgcn_s_barrier();
        asm volatile("" ::: "memory");

        // phase 1: stage rest, compute j=1
        if (it + 2 < 16) ISS_H2(nxt, ko);
        __builtin_amdgcn_sched_barrier(0);
        PHASE(cur, 1);

        // iter-end: wait for buf(it+1) (6 loads issued 1 iter ago); keep 6 in flight
        if (it < 14)       asm volatile("s_waitcnt vmcnt(6)" ::: "memory");
        else if (it == 14) asm volatile("s_waitcnt vmcnt(0)" ::: "memory");
        __builtin_amdgcn_s_barrier();
        asm volatile("" ::: "memory");
    }
    #undef PHASE
    #undef ISS_H1
    #undef ISS_H2

    // ----- partial store into packed pf region -----
    float* pw = pf + pbase + (size_t)sk * 256 * ld;
    #pragma unroll
    for (int rb = 0; rb < 2; ++rb) {
        const int rowb = mt * 128 + wm * 64 + rb * 32 + 4 * lh;
        #pragma unroll
        for (int e = 0; e < 16; ++e) {
            const int row = rowb + (e & 3) + 8 * (e >> 2);
            #pragma unroll
            for (int cb = 0; cb < 4; ++cb)
                pw[(size_t)row * ld + nt * 512 + wn * 128 + cb * 32 + l31] = acc[rb][cb][e];
        }
    }
}

// ---------------- branch decode for packed pf ----------------
__device__ __forceinline__ void pf_decode(int c, size_t& base, int& nsl, int& ld, int& cl) {
    if (c < 2048)      { base = 0;      nsl = 4; ld = 2048; cl = c; }
    else if (c < 6144) { base = PF_B1;  nsl = 8; ld = 4096; cl = c - 2048; }
    else               { base = PF_B2;  nsl = 4; ld = 2048; cl = c - 6144; }
}

// ---------------- epi0: slot-sum + relu*P/M + hi/lo re-split ----------------
__global__ void k_epi0(const float* __restrict__ pf,
                       const float* __restrict__ Pv, const float* __restrict__ Mv,
                       unsigned short* __restrict__ Yhi, unsigned short* __restrict__ Ylo) {
    int e = (blockIdx.x * 256 + threadIdx.x) * 4;   // over [256][8192]
    int m = e >> 13, c = e & 8191;
    size_t base; int nsl, ld, cl;
    pf_decode(c, base, nsl, ld, cl);
    const float* p0 = pf + base + (size_t)m * ld + cl;
    const size_t sstr = (size_t)256 * ld;
    float vs[4] = {0.f, 0.f, 0.f, 0.f};
    for (int s = 0; s < nsl; ++s) {
        float4 v = *(const float4*)(p0 + (size_t)s * sstr);
        vs[0] += v.x; vs[1] += v.y; vs[2] += v.z; vs[3] += v.w;
    }
    float4 pv = *(const float4*)(Pv + c);
    float4 mv = *(const float4*)(Mv + c);
    float pa[4] = {pv.x, pv.y, pv.z, pv.w};
    float ma[4] = {mv.x, mv.y, mv.z, mv.w};
    short hv[4], lv[4];
    #pragma unroll
    for (int j = 0; j < 4; ++j) {
        float y = fmaxf(vs[j], 0.f) * pa[j] + fmaxf(-vs[j], 0.f) * ma[j];
        unsigned short hb = rne_bf16(y);
        float hf = __builtin_bit_cast(float, (unsigned int)hb << 16);
        hv[j] = (short)hb;
        lv[j] = (short)rne_bf16(y - hf);
    }
    short4v h = {hv[0], hv[1], hv[2], hv[3]};
    short4v lo = {lv[0], lv[1], lv[2], lv[3]};
    *(short4v*)(Yhi + (size_t)m * IN_ + c) = h;
    *(short4v*)(Ylo + (size_t)m * IN_ + c) = lo;
}

// ---------------- epi1s: slot-sum + relu*P/M + sum over S -> hsum ----------------
__global__ void k_epi1s(const float* __restrict__ pf,
                        const float* __restrict__ Pv, const float* __restrict__ Mv,
                        float* __restrict__ hsum) {
    int e = (blockIdx.x * 256 + threadIdx.x) * 4;   // over [32][8192]
    int b = e >> 13, c = e & 8191;
    size_t base; int nsl, ld, cl;
    pf_decode(c, base, nsl, ld, cl);
    const size_t sstr = (size_t)256 * ld;
    float4 pv = *(const float4*)(Pv + c);
    float4 mv = *(const float4*)(Mv + c);
    float pa[4] = {pv.x, pv.y, pv.z, pv.w};
    float ma[4] = {mv.x, mv.y, mv.z, mv.w};
    float hs[4] = {0.f, 0.f, 0.f, 0.f};
    for (int q = 0; q < 8; ++q) {
        const int m = b * 8 + q;
        const float* p0 = pf + base + (size_t)m * ld + cl;
        float vs[4] = {0.f, 0.f, 0.f, 0.f};
        for (int s = 0; s < nsl; ++s) {
            float4 v = *(const float4*)(p0 + (size_t)s * sstr);
            vs[0] += v.x; vs[1] += v.y; vs[2] += v.z; vs[3] += v.w;
        }
        #pragma unroll
        for (int j = 0; j < 4; ++j)
            hs[j] += fmaxf(vs[j], 0.f) * pa[j] + fmaxf(-vs[j], 0.f) * ma[j];
    }
    *(float4*)(hsum + (size_t)b * IN_ + c) = *(float4*)hs;
}

// ---------------- MLP split-K partial GEMM (BW-shaped) ----------------
template<int KC>
__global__ __launch_bounds__(256) void k_mlp3(
    const float* __restrict__ X, const float* __restrict__ W,
    float* __restrict__ P, int K, int H)
{
    __shared__ float Xs[32][KC];
    const int tid = threadIdx.x;
    const int lane = tid & 63;
    const int mg = tid >> 6;
    const int h = (blockIdx.x * 64 + lane) * 4;
    const int c = blockIdx.y, k0 = c * KC;

    for (int i = tid * 4; i < 32 * KC; i += 1024) {
        int m = i / KC, kk = i % KC;
        *(float4*)&Xs[m][kk] = *(const float4*)(X + (size_t)m * K + k0 + kk);
    }
    __syncthreads();

    float4 acc[8];
    #pragma unroll
    for (int m = 0; m < 8; ++m) acc[m] = {0.f, 0.f, 0.f, 0.f};

    const float* wp = W + (size_t)k0 * H + h;
    for (int kk = 0; kk < KC; kk += 4) {
        float4 w4[4];
        #pragma unroll
        for (int u = 0; u < 4; ++u)
            w4[u] = *(const float4*)(wp + (size_t)(kk + u) * H);
        #pragma unroll
        for (int m = 0; m < 8; ++m) {
            float4 xv = *(const float4*)&Xs[mg * 8 + m][kk];
            acc[m].x = fmaf(xv.x, w4[0].x, acc[m].x);
            acc[m].y = fmaf(xv.x, w4[0].y, acc[m].y);
            acc[m].z = fmaf(xv.x, w4[0].z, acc[m].z);
            acc[m].w = fmaf(xv.x, w4[0].w, acc[m].w);
            acc[m].x = fmaf(xv.y, w4[1].x, acc[m].x);
            acc[m].y = fmaf(xv.y, w4[1].y, acc[m].y);
            acc[m].z = fmaf(xv.y, w4[1].z, acc[m].z);
            acc[m].w = fmaf(xv.y, w4[1].w, acc[m].w);
            acc[m].x = fmaf(xv.z, w4[2].x, acc[m].x);
            acc[m].y = fmaf(xv.z, w4[2].y, acc[m].y);
            acc[m].z = fmaf(xv.z, w4[2].z, acc[m].z);
            acc[m].w = fmaf(xv.z, w4[2].w, acc[m].w);
            acc[m].x = fmaf(xv.w, w4[3].x, acc[m].x);
            acc[m].y = fmaf(xv.w, w4[3].y, acc[m].y);
            acc[m].z = fmaf(xv.w, w4[3].z, acc[m].z);
            acc[m].w = fmaf(xv.w, w4[3].w, acc[m].w);
        }
    }
    #pragma unroll
    for (int m = 0; m < 8; ++m)
        *(float4*)(P + ((size_t)c * 32 + mg * 8 + m) * H + h) = acc[m];
}

// ---------------- reduce partials + bias (+relu), float4 ----------------
__global__ void k_reduce4(const float* __restrict__ P, const float* __restrict__ bias,
                          float* __restrict__ Y, int NC, int MH4, int H, int do_relu) {
    int idx = blockIdx.x * 256 + threadIdx.x;
    if (idx >= MH4) return;
    int h0 = (idx * 4) % H;
    float4 s = *(const float4*)(bias + h0);
    for (int c = 0; c < NC; ++c) {
        float4 v = *(const float4*)(P + (size_t)c * MH4 * 4 + (size_t)idx * 4);
        s.x += v.x; s.y += v.y; s.z += v.z; s.w += v.w;
    }
    if (do_relu) {
        s.x = fmaxf(s.x, 0.f); s.y = fmaxf(s.y, 0.f);
        s.z = fmaxf(s.z, 0.f); s.w = fmaxf(s.w, 0.f);
    }
    *(float4*)(Y + (size_t)idx * 4) = s;
}

extern "C" void kernel_launch(void* const* d_in, const int* in_sizes, int n_in,
                              void* d_out, int out_size, void* d_ws, size_t ws_size,
                              hipStream_t stream) {
    const float* xs0  = (const float*)d_in[0];
    const float* xs1  = (const float*)d_in[1];
    const float* xs2  = (const float*)d_in[2];
    const float* L0   = (const float*)d_in[3];
    const float* L1   = (const float*)d_in[4];
    const float* L2   = (const float*)d_in[5];
    const float* Wc0  = (const float*)d_in[6];
    const float* Wc1  = (const float*)d_in[7];
    const float* Wc2  = (const float*)d_in[8];
    const float* W_in = (const float*)d_in[9];
    const float* b_in = (const float*)d_in[10];
    const float* W_h  = (const float*)d_in[11];
    const float* b_h  = (const float*)d_in[12];
    const float* W_out= (const float*)d_in[13];
    const float* b_out= (const float*)d_in[14];

    char* w = (char*)d_ws;
    float*          PM  = (float*)w;          w += (size_t)4 * IN_ * 4;          // 128 KB
    unsigned short* Lb  = (unsigned short*)w; w += (size_t)L_TOT * 2;            // 50.3 MB
    unsigned short* Xhi = (unsigned short*)w; w += (size_t)BS_ * IN_ * 2;        // 4 MB
    unsigned short* Xlo = (unsigned short*)w; w += (size_t)BS_ * IN_ * 2;        // 4 MB
    float*          pf  = (float*)w;          w += (size_t)PF_TOT * 4;           // 48 MB
    float*          hsum= (float*)w;          w += (size_t)32 * IN_ * 4;         // 1 MB
    float*          p1  = pf;                 // alias: pf free after k_epi1s
    float*          h1  = (float*)w;          w += (size_t)32 * H_ * 4;
    float*          p2  = (float*)w;          w += (size_t)32 * 32 * H_ * 4;     // 4 MB
    float*          h2  = (float*)w;          w += (size_t)32 * H_ * 4;
    float*          p3  = (float*)w;          w += (size_t)32 * 32 * OUT_ * 4;   // 1 MB
    unsigned short* Yhi = Xhi;                // alias: X dead after gemm1
    unsigned short* Ylo = Xlo;

    k_pre<<<3592, 256, 0, stream>>>(L0, L1, L2, Lb, xs0, xs1, xs2, Xhi, Xlo,
                                    Wc0, Wc1, Wc2, PM);

    k_gemm<<<192, 512, 0, stream>>>(Xhi, Xlo, Lb, pf);
    k_epi0<<<2048, 256, 0, stream>>>(pf, PM + 0 * IN_, PM + 1 * IN_, Yhi, Ylo);
    k_gemm<<<192, 512, 0, stream>>>(Yhi, Ylo, Lb, pf);
    k_epi1s<<<256, 256, 0, stream>>>(pf, PM + 2 * IN_, PM + 3 * IN_, hsum);

    {   // [32,8192]@[8192,1024]: grid (4 h-tiles, 128 k-chunks of 64)
        dim3 g(4, 128);
        k_mlp3<64><<<g, 256, 0, stream>>>(hsum, W_in, p1, IN_, H_);
        k_reduce4<<<32, 256, 0, stream>>>(p1, b_in, h1, 128, 8192, H_, 1);
    }
    {   // [32,1024]@[1024,1024]: grid (4, 32 chunks of 32)
        dim3 g(4, 32);
        k_mlp3<32><<<g, 256, 0, stream>>>(h1, W_h, p2, H_, H_);
        k_reduce4<<<32, 256, 0, stream>>>(p2, b_h, h2, 32, 8192, H_, 1);
    }
    {   // [32,1024]@[1024,256]: grid (1, 32 chunks of 32)
        dim3 g(1, 32);
        k_mlp3<32><<<g, 256, 0, stream>>>(h2, W_out, p3, H_, OUT_);
        k_reduce4<<<8, 256, 0, stream>>>(p3, b_out, (float*)d_out, 32, 2048, OUT_, 0);
    }
}